// Round 11
// baseline (141.772 us; speedup 1.0000x reference)
//
#include <hip/hip_runtime.h>
#include <hip/hip_fp16.h>

#define NPTS 256
#define TABLE 4096
#define N_ENC 24
#define P_TOTAL (NPTS * NPTS)   // 65536
#define PRIME1 2654435761u
#define PRIME2 805459861u
#define ENTRY_H2 32             // half2 slots per 128B entry (24 used, 8 pad)
#define N_CENT 28211            // total compacted entries (3.44 MB)
#define S_BYTES 45824           // levels 0-5: 358 entries * 128B, staged in LDS
#define PTS_PER_BLK 64

typedef int   i32x4 __attribute__((ext_vector_type(4)));
typedef float f32x4 __attribute__((ext_vector_type(4)));

// Compact layout: levels 0-10 dense by lattice index (D=2R+1 per axis),
// levels 11-15 full 4096 hashed buckets.
// bases B[l]; entries: {27,27,27,27,125,125,343,729,729,2197,3375,4096x5}

// ---------------------------------------------------------------------------
// Rebuild: compacted fp16 table. For lattice levels, evaluate the hash per
// cell (collisions duplicate values -> results identical to reference).
// ---------------------------------------------------------------------------
__global__ __launch_bounds__(256) void k_build(const float2* __restrict__ src,
                                               __half2* __restrict__ T2) {
    const int tid = blockIdx.x * 256 + threadIdx.x;
    if (tid >= N_CENT * N_ENC) return;
    const int t = tid % N_ENC;
    const int e = tid / N_ENC;
    constexpr int B[17] = {0,27,54,81,108,233,358,701,1430,2159,4356,
                           7731,11827,15923,20019,24115,28211};
    constexpr int Rv[16] = {1,1,1,1,2,2,3,4,4,6,7,8,10,13,16,19};
#pragma unroll
    for (int l = 0; l < 16; ++l) {
        if (e >= B[l] && e < B[l + 1]) {
            const int local = e - B[l];
            int hash;
            if (l <= 10) {
                const int R = Rv[l], D = 2 * R + 1;
                const int x = local / (D * D), rem = local - x * (D * D);
                const int y = rem / D, z = rem - y * D;
                hash = (int)((((unsigned)(x - R))
                            ^ ((unsigned)(y - R)) * PRIME1
                            ^ ((unsigned)(z - R)) * PRIME2) & (TABLE - 1u));
            } else {
                hash = local;
            }
            const float2 f = src[((t * 16 + l) * TABLE) + hash];
            T2[(size_t)e * ENTRY_H2 + t] =
                __halves2half2(__float2half_rn(f.x), __float2half_rn(f.y));
        }
    }
}

// ---------------------------------------------------------------------------
// Main kernel (R8 structure + LDS staging of levels 0-5).
// Block = 256 threads = 4 waves; processes 64 consecutive points (one i-row
// slice). Levels 0-5 (lane groups l8<3, both h) read from LDS; levels 6-15
// from L2. lane = l8*8 + q; l8 owns level pair {2l8, 2l8+1}; q = 16B chunk.
// ---------------------------------------------------------------------------
__global__ __launch_bounds__(256) void k_main(const float* __restrict__ xyz,
                                              const char* __restrict__ Tb,
                                              float* __restrict__ out) {
    __shared__ __align__(16) char s_tab[S_BYTES];
    for (int n = threadIdx.x; n < S_BYTES / 16; n += 256)
        ((i32x4*)s_tab)[n] = ((const i32x4*)Tb)[n];
    __syncthreads();

    const int lane = threadIdx.x & 63;
    const int w    = threadIdx.x >> 6;
    const int l8 = lane >> 3;    // level pair index: levels {2l8, 2l8+1}
    const int q  = lane & 7;     // 16B chunk

    const int pbase = blockIdx.x * PTS_PER_BLK;
    const int i = pbase >> 8;                    // same i for whole block
    const float xi = xyz[3 * i], yi = xyz[3 * i + 1], zi = xyz[3 * i + 2];

    // Packed per-level constants (level order):
    // RES = floor(20^(fl(1/15)*l)) = {1,1,1,1,2,2,3,4,4,6,7,8,10,13,16,19}
    const unsigned long long RESLO = 0x0403020201010101ull;
    const unsigned long long RESHI = 0x13100D0A08070604ull;
    const unsigned long long DLO   = 0x0907050503030303ull;  // D=2R+1
    const unsigned long long DHI   = 0x00000000000F0D09ull;
    const unsigned long long C0    = 0x00510036001B0000ull;  // bases l0-3
    const unsigned long long C1    = 0x02BD016600E9006Cull;  // l4-7
    const unsigned long long C2    = 0x1E331104086F0596ull;  // l8-11
    const unsigned long long C3    = 0x5E334E333E332E33ull;  // l12-15

#pragma unroll 1
    for (int it = 0; it < PTS_PER_BLK / 4; ++it) {
        const int p = pbase + w * (PTS_PER_BLK / 4) + it;
        const int j = p & 255;
        const float rx = xi - xyz[3 * j + 0];
        const float ry = yi - xyz[3 * j + 1];
        const float rz = zi - xyz[3 * j + 2];

        // Per-lane state for its two levels (h: level = 2*l8 + h)
        __half2 pwh[2][4], zuh[2], zwh[2];
        unsigned offs[16];
#pragma unroll
        for (int h = 0; h < 2; ++h) {
            const int level = 2 * l8 + h;
            const unsigned shift8 = (level & 7) * 8;
            const float res = (float)((((l8 < 4) ? RESLO : RESHI) >> shift8) & 0xFF);
            const int   R   = (int)res;
            const int   D   = (int)((((l8 < 4) ? DLO : DHI) >> shift8) & 0xFF);
            const unsigned long long Bw = (l8 < 2) ? C0 : (l8 < 4) ? C1
                                        : (l8 < 6) ? C2 : C3;
            const unsigned base = (unsigned)((Bw >> ((level & 3) * 16)) & 0xFFFF);
            const bool latt = (l8 <= 5 - h);        // level <= 10

            const float sx = rx * res, sy = ry * res, sz = rz * res;
            const float bx = floorf(sx), by = floorf(sy), bz = floorf(sz);
            const float wxx = sx - bx, wyy = sy - by, wzz = sz - bz;
            const float uxx = 1.0f - wxx, uyy = 1.0f - wyy, uzz = 1.0f - wzz;
            pwh[h][0] = __float2half2_rn(uxx * uyy);
            pwh[h][1] = __float2half2_rn(wxx * uyy);
            pwh[h][2] = __float2half2_rn(uxx * wyy);
            pwh[h][3] = __float2half2_rn(wxx * wyy);
            zuh[h] = __float2half2_rn(uzz);
            zwh[h] = __float2half2_rn(wzz);

            const int bxi = (int)bx, byi = (int)by, bzi = (int)bz;
            // hashed path bases
            const unsigned hx0 = (unsigned)bxi,          hx1 = hx0 + 1u;
            const unsigned hy0 = (unsigned)byi * PRIME1, hy1 = hy0 + PRIME1;
            const unsigned hz0 = (unsigned)bzi * PRIME2, hz1 = hz0 + PRIME2;
            const unsigned hbase = (base << 7) + ((unsigned)q << 4);
            // lattice path base + strides
            const int iA = ((bxi + R) * D + (byi + R)) * D + (bzi + R);
            const unsigned addrC = ((base + (unsigned)iA) << 7) + ((unsigned)q << 4);
            const unsigned DDs = (unsigned)(D * D) << 7;
            const unsigned Dbs = (unsigned)D << 7;

#pragma unroll
            for (int c = 0; c < 8; ++c) {
                unsigned offC = addrC;
                if (c & 1) offC += DDs;
                if (c & 2) offC += Dbs;
                if (c & 4) offC += 128u;
                const unsigned hsh = ((c & 1) ? hx1 : hx0)
                                   ^ ((c & 2) ? hy1 : hy0)
                                   ^ ((c & 4) ? hz1 : hz0);
                const unsigned offH = hbase + ((hsh & (TABLE - 1u)) << 7);
                offs[c * 2 + h] = latt ? offC : offH;
            }
        }

        // ---- Rolling 8-deep gather/consume pipeline (k = c*2 + h) ----
        // groups l8<3 = levels 0-5 -> LDS; groups l8>=3 -> global (L2).
        i32x4 raw[16];
#pragma unroll
        for (int k = 0; k < 8; ++k) {
            if (l8 < 3) raw[k] = *(const i32x4*)(s_tab + offs[k]);
            else        raw[k] = *(const i32x4*)(Tb + offs[k]);
        }

        __half2 accA[4] = {}, accB[4] = {};
#pragma unroll
        for (int k = 0; k < 16; ++k) {
            if (k < 8) {
                if (l8 < 3) raw[k + 8] = *(const i32x4*)(s_tab + offs[k + 8]);
                else        raw[k + 8] = *(const i32x4*)(Tb + offs[k + 8]);
            }
            const int c = k >> 1, h = k & 1;
            const __half2 wh = __hmul2(pwh[h][c & 3], (c & 4) ? zwh[h] : zuh[h]);
            __half2* acc = h ? accB : accA;      // h compile-time
#pragma unroll
            for (int r = 0; r < 4; ++r) {
                __half2 hv;
                __builtin_memcpy(&hv, (const char*)&raw[k] + 4 * r, 4);
                acc[r] = __hfma2(hv, wh, acc[r]);
            }
        }

        // lane (l8, q<6) holds t=4q+r, levels {2l8, 2l8+1} -> one 16B store.
        // Wave covers out[t][p][0..31] as full 128B lines.
        if (q < 6) {
#pragma unroll
            for (int r = 0; r < 4; ++r) {
                const int t = 4 * q + r;
                const float2 a = __half22float2(accA[r]);   // level 2l8
                const float2 b = __half22float2(accB[r]);   // level 2l8+1
                f32x4 v;
                v.x = a.x; v.y = a.y; v.z = b.x; v.w = b.y;
                float* dst = out + (size_t)t * ((size_t)P_TOTAL * 32)
                                 + (size_t)p * 32 + 4 * l8;
                __builtin_nontemporal_store(v, (f32x4*)dst);
            }
        }
    }
}

extern "C" void kernel_launch(void* const* d_in, const int* in_sizes, int n_in,
                              void* d_out, int out_size, void* d_ws, size_t ws_size,
                              hipStream_t stream) {
    const float* xyz    = (const float*)d_in[0];
    const float* tables = (const float*)d_in[1];
    float* out = (float*)d_out;

    // workspace: 28211 * 128B = 3.44 MB (< per-XCD L2)
    const int nb = (N_CENT * N_ENC + 255) / 256;
    k_build<<<nb, 256, 0, stream>>>((const float2*)tables, (__half2*)d_ws);
    k_main<<<P_TOTAL / PTS_PER_BLK, 256, 0, stream>>>(xyz, (const char*)d_ws, out);
}

// Round 12
// 69.581 us; speedup vs baseline: 2.0375x; 2.0375x over previous
//
#include <hip/hip_runtime.h>
#include <hip/hip_fp16.h>

#define NPTS 256
#define TABLE 4096
#define N_ENC 24
#define P_TOTAL (NPTS * NPTS)   // 65536
#define PRIME1 2654435761u
#define PRIME2 805459861u
#define ENTRY_H2 32             // half2 slots per 128B entry (24 used, 8 pad)
#define N_CENT 28211            // total compacted entries (3.44 MB)

typedef int   i32x4 __attribute__((ext_vector_type(4)));
typedef float f32x4 __attribute__((ext_vector_type(4)));

// Compact layout: levels 0-10 dense by lattice index (D=2R+1 per axis),
// levels 11-15 full 4096 hashed buckets.
// bases B[l]; entries: {27,27,27,27,125,125,343,729,729,2197,3375,4096x5}

// ---------------------------------------------------------------------------
// Rebuild: compacted fp16 table. For lattice levels, evaluate the hash per
// cell (collisions duplicate values -> results identical to reference).
// ---------------------------------------------------------------------------
__global__ __launch_bounds__(256) void k_build(const float2* __restrict__ src,
                                               __half2* __restrict__ T2) {
    const int tid = blockIdx.x * 256 + threadIdx.x;
    if (tid >= N_CENT * N_ENC) return;
    const int t = tid % N_ENC;
    const int e = tid / N_ENC;
    constexpr int B[17] = {0,27,54,81,108,233,358,701,1430,2159,4356,
                           7731,11827,15923,20019,24115,28211};
    constexpr int Rv[16] = {1,1,1,1,2,2,3,4,4,6,7,8,10,13,16,19};
#pragma unroll
    for (int l = 0; l < 16; ++l) {
        if (e >= B[l] && e < B[l + 1]) {
            const int local = e - B[l];
            int hash;
            if (l <= 10) {
                const int R = Rv[l], D = 2 * R + 1;
                const int x = local / (D * D), rem = local - x * (D * D);
                const int y = rem / D, z = rem - y * D;
                hash = (int)((((unsigned)(x - R))
                            ^ ((unsigned)(y - R)) * PRIME1
                            ^ ((unsigned)(z - R)) * PRIME2) & (TABLE - 1u));
            } else {
                hash = local;
            }
            const float2 f = src[((t * 16 + l) * TABLE) + hash];
            T2[(size_t)e * ENTRY_H2 + t] =
                __halves2half2(__float2half_rn(f.x), __float2half_rn(f.y));
        }
    }
}

// ---------------------------------------------------------------------------
// Main kernel (exact R8 structure; probe changes marked).
// One wave per point p. lane = l8*8 + q:
//   l8: this lane owns the level PAIR {2*l8, 2*l8+1}
//   q : 16B chunk of the 128B entry (t = 4q..4q+3; q=6,7 are PADDING)
// PROBE 1: gathers masked to q<6 (-25% lane-requests, SAME line set).
// PROBE 2: p scalarized via readfirstlane -> xyz via s_load.
// ---------------------------------------------------------------------------
__global__ __launch_bounds__(256) void k_main(const float* __restrict__ xyz,
                                              const char* __restrict__ Tb,
                                              float* __restrict__ out) {
    const int lane = threadIdx.x & 63;
    const int pv = blockIdx.x * 4 + (threadIdx.x >> 6);
    const int p  = __builtin_amdgcn_readfirstlane(pv);   // wave-uniform
    const int i = p >> 8, j = p & 255;
    const int l8 = lane >> 3;    // level pair index
    const int q  = lane & 7;     // 16B chunk

    const float rx = xyz[i * 3 + 0] - xyz[j * 3 + 0];
    const float ry = xyz[i * 3 + 1] - xyz[j * 3 + 1];
    const float rz = xyz[i * 3 + 2] - xyz[j * 3 + 2];

    // Packed per-level constants (level order):
    // RES = floor(20^(fl(1/15)*l)) = {1,1,1,1,2,2,3,4,4,6,7,8,10,13,16,19}
    const unsigned long long RESLO = 0x0403020201010101ull;
    const unsigned long long RESHI = 0x13100D0A08070604ull;
    const unsigned long long DLO   = 0x0907050503030303ull;  // D=2R+1
    const unsigned long long DHI   = 0x00000000000F0D09ull;
    const unsigned long long C0    = 0x00510036001B0000ull;  // bases l0-3
    const unsigned long long C1    = 0x02BD016600E9006Cull;  // l4-7
    const unsigned long long C2    = 0x1E331104086F0596ull;  // l8-11
    const unsigned long long C3    = 0x5E334E333E332E33ull;  // l12-15

    // Per-lane state for its two levels (h: level = 2*l8 + h)
    __half2 pwh[2][4], zuh[2], zwh[2];
    unsigned offs[16];
#pragma unroll
    for (int h = 0; h < 2; ++h) {
        const int level = 2 * l8 + h;
        const unsigned shift8 = (level & 7) * 8;
        const float res = (float)((((l8 < 4) ? RESLO : RESHI) >> shift8) & 0xFF);
        const int   R   = (int)res;
        const int   D   = (int)((((l8 < 4) ? DLO : DHI) >> shift8) & 0xFF);
        const unsigned long long Bw = (l8 < 2) ? C0 : (l8 < 4) ? C1
                                    : (l8 < 6) ? C2 : C3;
        const unsigned base = (unsigned)((Bw >> ((level & 3) * 16)) & 0xFFFF);
        const bool latt = (l8 <= 5 - h);        // level <= 10

        const float sx = rx * res, sy = ry * res, sz = rz * res;
        const float bx = floorf(sx), by = floorf(sy), bz = floorf(sz);
        const float wxx = sx - bx, wyy = sy - by, wzz = sz - bz;
        const float uxx = 1.0f - wxx, uyy = 1.0f - wyy, uzz = 1.0f - wzz;
        pwh[h][0] = __float2half2_rn(uxx * uyy);
        pwh[h][1] = __float2half2_rn(wxx * uyy);
        pwh[h][2] = __float2half2_rn(uxx * wyy);
        pwh[h][3] = __float2half2_rn(wxx * wyy);
        zuh[h] = __float2half2_rn(uzz);
        zwh[h] = __float2half2_rn(wzz);

        const int bxi = (int)bx, byi = (int)by, bzi = (int)bz;
        // hashed path bases
        const unsigned hx0 = (unsigned)bxi,          hx1 = hx0 + 1u;
        const unsigned hy0 = (unsigned)byi * PRIME1, hy1 = hy0 + PRIME1;
        const unsigned hz0 = (unsigned)bzi * PRIME2, hz1 = hz0 + PRIME2;
        const unsigned hbase = (base << 7) + ((unsigned)q << 4);
        // lattice path base + strides
        const int iA = ((bxi + R) * D + (byi + R)) * D + (bzi + R);
        const unsigned addrC = ((base + (unsigned)iA) << 7) + ((unsigned)q << 4);
        const unsigned DDs = (unsigned)(D * D) << 7;
        const unsigned Dbs = (unsigned)D << 7;

#pragma unroll
        for (int c = 0; c < 8; ++c) {
            unsigned offC = addrC;
            if (c & 1) offC += DDs;
            if (c & 2) offC += Dbs;
            if (c & 4) offC += 128u;
            const unsigned hsh = ((c & 1) ? hx1 : hx0)
                               ^ ((c & 2) ? hy1 : hy0)
                               ^ ((c & 4) ? hz1 : hz0);
            const unsigned offH = hbase + ((hsh & (TABLE - 1u)) << 7);
            offs[c * 2 + h] = latt ? offC : offH;
        }
    }

    // ---- Rolling 8-deep gather/consume pipeline (k = c*2 + h) ----
    // PROBE: q=6,7 chunks are padding -> mask those lanes' gathers out.
    // Line set per instruction is unchanged (q=4,5 cover the 2nd 64B line).
    i32x4 raw[16] = {};
    const bool act = (q < 6);
#pragma unroll
    for (int k = 0; k < 8; ++k)
        if (act) raw[k] = *(const i32x4*)(Tb + offs[k]);

    __half2 accA[4] = {}, accB[4] = {};
#pragma unroll
    for (int k = 0; k < 16; ++k) {
        if (k < 8) {
            if (act) raw[k + 8] = *(const i32x4*)(Tb + offs[k + 8]);
        }
        const int c = k >> 1, h = k & 1;
        const __half2 wh = __hmul2(pwh[h][c & 3], (c & 4) ? zwh[h] : zuh[h]);
        __half2* acc = h ? accB : accA;      // h compile-time
#pragma unroll
        for (int r = 0; r < 4; ++r) {
            __half2 hv;
            __builtin_memcpy(&hv, (const char*)&raw[k] + 4 * r, 4);
            acc[r] = __hfma2(hv, wh, acc[r]);
        }
    }

    // lane (l8, q<6) holds t=4q+r, levels {2l8, 2l8+1} -> one 16B store.
    // Wave covers out[t][p][0..31] as full 128B lines.
    if (q < 6) {
#pragma unroll
        for (int r = 0; r < 4; ++r) {
            const int t = 4 * q + r;
            const float2 a = __half22float2(accA[r]);   // level 2l8
            const float2 b = __half22float2(accB[r]);   // level 2l8+1
            f32x4 v;
            v.x = a.x; v.y = a.y; v.z = b.x; v.w = b.y;
            float* dst = out + (size_t)t * ((size_t)P_TOTAL * 32)
                             + (size_t)p * 32 + 4 * l8;
            __builtin_nontemporal_store(v, (f32x4*)dst);
        }
    }
}

extern "C" void kernel_launch(void* const* d_in, const int* in_sizes, int n_in,
                              void* d_out, int out_size, void* d_ws, size_t ws_size,
                              hipStream_t stream) {
    const float* xyz    = (const float*)d_in[0];
    const float* tables = (const float*)d_in[1];
    float* out = (float*)d_out;

    // workspace: 28211 * 128B = 3.44 MB (< per-XCD L2)
    const int nb = (N_CENT * N_ENC + 255) / 256;
    k_build<<<nb, 256, 0, stream>>>((const float2*)tables, (__half2*)d_ws);
    k_main<<<P_TOTAL / 4, 256, 0, stream>>>(xyz, (const char*)d_ws, out);
}